// Round 4
// baseline (8698.572 us; speedup 1.0000x reference)
//
#include <hip/hip_runtime.h>
#include <hip/hip_bf16.h>
#include <stdint.h>

typedef __bf16 bf16_t;
typedef bf16_t bf16x8 __attribute__((ext_vector_type(8)));
typedef float  f32x4  __attribute__((ext_vector_type(4)));
typedef float  f32x16 __attribute__((ext_vector_type(16)));

#define I_DIM 512
#define H_DIM 1024
#define B_DIM 64
#define S_DIM 512
#define G4    4096   // 4*H
#define CHUNK 32     // steps per chunk
#define NCHUNK (S_DIM / CHUNK)

// ---------------- workspace layout (bytes) — total ~34 MB ----------------
#define O_WXT   0x0000000ULL  // [4096][512]  bf16 = 4 MB
#define O_WHT   0x0400000ULL  // [4096][1024] bf16 = 8 MB
#define O_BIAS  0x0C00000ULL  // [4096] f32 = 16 KB
#define O_CST   0x0C10000ULL  // [64][1024] f32 = 256 KB
#define O_FLAGS 0x0C50000ULL  // 256 * u32 = 1 KB
#define O_HBUF  0x0D00000ULL  // 33 ring buffers * 128 KB (A-frag order) = 4.125 MB
#define O_XP    0x1200000ULL  // [CHUNK*64][4096] bf16 = 16 MB

__device__ __forceinline__ float sigm(float x)      { return 1.f / (1.f + __expf(-x)); }
__device__ __forceinline__ float tanh_fast(float x) { return 1.f - 2.f / (__expf(2.f * x) + 1.f); }

// Write-through u32 store (sc0 sc1): lands in LLC, no wbl2 needed.
__device__ __forceinline__ void st_u32_llc(uint32_t* p, uint32_t v) {
    __hip_atomic_store(p, v, __ATOMIC_RELAXED, __HIP_MEMORY_SCOPE_AGENT);
}

// Packed gate-column permutation: packed col p = q*32 + g*8 + jj  <->  hidden j = q*8+jj, gate g (0:i 1:f 2:g 3:o)

__global__ void k_pack_wx(const float* __restrict__ w0, const float* __restrict__ w1,
                          const float* __restrict__ w2, const float* __restrict__ w3,
                          bf16_t* __restrict__ wxt) {
    int tid = blockIdx.x * 256 + threadIdx.x;
    int k = tid >> 12;
    int p = tid & 4095;
    int q = p >> 5, g = (p >> 3) & 3, jj = p & 7;
    int j = q * 8 + jj;
    const float* src = (g == 0) ? w0 : (g == 1) ? w1 : (g == 2) ? w2 : w3;
    wxt[(size_t)p * I_DIM + k] = (bf16_t)src[k * H_DIM + j];
}

__global__ void k_pack_wh(const float* __restrict__ w0, const float* __restrict__ w1,
                          const float* __restrict__ w2, const float* __restrict__ w3,
                          bf16_t* __restrict__ wht) {
    int tid = blockIdx.x * 256 + threadIdx.x;
    int k = tid >> 12;
    int p = tid & 4095;
    int q = p >> 5, g = (p >> 3) & 3, jj = p & 7;
    int j = q * 8 + jj;
    const float* src = (g == 0) ? w0 : (g == 1) ? w1 : (g == 2) ? w2 : w3;
    wht[(size_t)p * H_DIM + k] = (bf16_t)src[k * H_DIM + j];
}

__global__ void k_pack_bias(const float* bi0, const float* bh0, const float* bi1, const float* bh1,
                            const float* bi2, const float* bh2, const float* bi3, const float* bh3,
                            float* __restrict__ bias) {
    int p = blockIdx.x * 256 + threadIdx.x;
    int q = p >> 5, g = (p >> 3) & 3, jj = p & 7;
    int j = q * 8 + jj;
    const float* a = (g == 0) ? bi0 : (g == 1) ? bi1 : (g == 2) ? bi2 : bi3;
    const float* b = (g == 0) ? bh0 : (g == 1) ? bh1 : (g == 2) ? bh2 : bh3;
    bias[p] = a[j] + b[j];
}

// ---------------- chunked x_proj GEMM ----------------
__global__ __launch_bounds__(256, 2) void k_xproj(
    const float* __restrict__ x, const bf16_t* __restrict__ wxt,
    const float* __restrict__ bias, bf16_t* __restrict__ xp, int r_base)
{
    __shared__ __align__(16) bf16_t Al[8 * 64 * 8];
    __shared__ __align__(16) bf16_t Bl[8 * 64 * 8];
    const int tid = threadIdx.x;
    const int n0 = blockIdx.x * 128;
    const int r0 = r_base + blockIdx.y * 128;
    const int wv = tid >> 6;
    const int lane = tid & 63;
    const int mq = wv >> 1, nq = wv & 1;
    f32x4 acc[4][4] = {};

    for (int kk = 0; kk < I_DIM; kk += 32) {
        __syncthreads();
        #pragma unroll
        for (int sidx = 0; sidx < 2; ++sidx) {
            int s = tid + sidx * 256;
            int mt = s >> 6, l = s & 63;
            int m = l & 15, kb = (l >> 4) * 8;
            int r = r0 + mt * 16 + m;
            int b = r & 63, si = r >> 6;
            const float* gp = x + ((size_t)(b * S_DIM + si)) * I_DIM + kk + kb;
            float4 v0 = *(const float4*)gp;
            float4 v1 = *(const float4*)(gp + 4);
            bf16x8 a;
            a[0] = (bf16_t)v0.x; a[1] = (bf16_t)v0.y; a[2] = (bf16_t)v0.z; a[3] = (bf16_t)v0.w;
            a[4] = (bf16_t)v1.x; a[5] = (bf16_t)v1.y; a[6] = (bf16_t)v1.z; a[7] = (bf16_t)v1.w;
            *(bf16x8*)&Al[s * 8] = a;
            bf16x8 bv = *(const bf16x8*)(wxt + (size_t)(n0 + mt * 16 + m) * I_DIM + kk + kb);
            *(bf16x8*)&Bl[s * 8] = bv;
        }
        __syncthreads();
        bf16x8 af[4], bfr[4];
        #pragma unroll
        for (int mt = 0; mt < 4; ++mt) af[mt]  = *(bf16x8*)&Al[((mq * 4 + mt) * 64 + lane) * 8];
        #pragma unroll
        for (int nt = 0; nt < 4; ++nt) bfr[nt] = *(bf16x8*)&Bl[((nq * 4 + nt) * 64 + lane) * 8];
        #pragma unroll
        for (int mt = 0; mt < 4; ++mt)
            #pragma unroll
            for (int nt = 0; nt < 4; ++nt)
                acc[mt][nt] = __builtin_amdgcn_mfma_f32_16x16x32_bf16(af[mt], bfr[nt], acc[mt][nt], 0, 0, 0);
    }
    const int l15 = lane & 15, quad = lane >> 4;
    #pragma unroll
    for (int nt = 0; nt < 4; ++nt) {
        int col = n0 + nq * 64 + nt * 16 + l15;
        float bv = bias[col];
        #pragma unroll
        for (int mt = 0; mt < 4; ++mt)
            #pragma unroll
            for (int r = 0; r < 4; ++r) {
                int row = r0 - r_base + mq * 64 + mt * 16 + quad * 4 + r;
                xp[(size_t)row * G4 + col] = (bf16_t)(acc[mt][nt][r] + bv);
            }
    }
}

// ---------------- persistent recurrent kernel (one chunk of CHUNK steps) ----------------
// Ring of 33 h step-buffers in MFMA A-fragment order [bh][ks][lane][8]:
//  - step tl reads buf[tl] (fresh address -> cached loads can never be stale
//    within a dispatch; dispatch-boundary acquire invalidates across chunks)
//  - step tl writes buf[tl+1] via write-through (sc0 sc1) u32 stores -> LLC
//  - A-loads are plain cached bf16x8 loads, perfectly coalesced (1 KB/inst),
//    L2-hit after first touch. (R3's sc0/sc1 bypass loads were the 13.7 us/step
//    wall: serialized single-transaction LLC accesses, 32 lines per inst.)
__global__ __launch_bounds__(64, 1) void k_lstm(
    const bf16_t* __restrict__ wht, const bf16_t* __restrict__ xp,
    bf16_t* __restrict__ hbuf, float* __restrict__ cstbuf,
    float* __restrict__ out, unsigned* __restrict__ flags, int t0)
{
    __shared__ __align__(16) bf16_t Blds[32768];   // 64 KB B-fragments [ks(64)][lane(64)][8]
    const int lane = threadIdx.x;
    const int wg = blockIdx.x;
    const int q  = wg >> 1;
    const int bh = wg & 1;

    // Stage WhT rows q*32..+31 into LDS in 32x32x16 B-fragment order.
    for (int i = 0; i < 64; ++i) {
        int task = lane + (i << 6);
        int c = task >> 7;
        int k = (task & 127) << 3;
        bf16x8 v = *(const bf16x8*)(wht + (((size_t)(q * 32 + c)) << 10) + k);
        int base = (((k >> 4) << 6) + c + (((k >> 3) & 1) << 5)) << 3;
        *(bf16x8*)&Blds[base] = v;
    }
    __syncthreads();

    const int col  = lane & 31;
    const int ksel = lane >> 5;
    const int gt   = (lane >> 3) & 3;  // 0:i 1:f 2:g 3:o
    const int jj   = lane & 7;

    int rrow[16];
    #pragma unroll
    for (int r = 0; r < 16; ++r) rrow[r] = (r & 3) + 8 * (r >> 2) + 4 * ksel;

    float cst[16];
    if (t0 == 0) {
        #pragma unroll
        for (int r = 0; r < 16; ++r) cst[r] = 0.f;
    } else {
        #pragma unroll
        for (int r = 0; r < 16; ++r)
            cst[r] = cstbuf[(bh * 32 + rrow[r]) * H_DIM + q * 8 + jj];
    }

    bf16_t xpr[16];
    #pragma unroll
    for (int r = 0; r < 16; ++r)
        xpr[r] = xp[(size_t)(bh * 32 + rrow[r]) * G4 + q * 32 + col];

    // writer scatter base (u32 units, within a step buffer):
    //   bh*16384 + ((q>>1)*64 + rrow[r] + 32*(q&1))*4 + (jj>>1)
    const int wbase = (bh << 14) + (((q >> 1) << 6) + ((q & 1) << 5)) * 4 + (jj >> 1);

    for (int tl = 0; tl < CHUNK; ++tl) {
        const int t = t0 + tl;
        const int rd = (tl == 0) ? ((t0 == 0) ? 0 : 32) : tl;
        // A-frag base: buffer rd, half bh, this lane's 8-elem slot.
        const bf16_t* ab = hbuf + ((size_t)rd << 16) + (bh << 15) + (lane << 3);

        f32x16 acc0 = {}, acc1 = {}, acc2 = {}, acc3 = {};
        #pragma unroll
        for (int ks = 0; ks < 64; ks += 4) {
            bf16x8 a0 = *(const bf16x8*)(ab + (ks + 0) * 512);
            bf16x8 a1 = *(const bf16x8*)(ab + (ks + 1) * 512);
            bf16x8 a2 = *(const bf16x8*)(ab + (ks + 2) * 512);
            bf16x8 a3 = *(const bf16x8*)(ab + (ks + 3) * 512);
            bf16x8 b0 = *(const bf16x8*)&Blds[(((ks + 0) << 6) + lane) << 3];
            bf16x8 b1 = *(const bf16x8*)&Blds[(((ks + 1) << 6) + lane) << 3];
            bf16x8 b2 = *(const bf16x8*)&Blds[(((ks + 2) << 6) + lane) << 3];
            bf16x8 b3 = *(const bf16x8*)&Blds[(((ks + 3) << 6) + lane) << 3];
            acc0 = __builtin_amdgcn_mfma_f32_32x32x16_bf16(a0, b0, acc0, 0, 0, 0);
            acc1 = __builtin_amdgcn_mfma_f32_32x32x16_bf16(a1, b1, acc1, 0, 0, 0);
            acc2 = __builtin_amdgcn_mfma_f32_32x32x16_bf16(a2, b2, acc2, 0, 0, 0);
            acc3 = __builtin_amdgcn_mfma_f32_32x32x16_bf16(a3, b3, acc3, 0, 0, 0);
        }
        f32x16 accs = acc0 + acc1 + acc2 + acc3;

        float act[16];
        #pragma unroll
        for (int r = 0; r < 16; ++r) {
            float pre = accs[r] + (float)xpr[r];
            act[r] = (gt == 2) ? tanh_fast(pre) : sigm(pre);
        }

        // h update: i-lanes own (row, j); pack bf16 pairs, write-through to buf[tl+1].
        uint32_t* hn = (uint32_t*)hbuf + ((size_t)(tl + 1) << 15);
        #pragma unroll
        for (int r = 0; r < 16; ++r) {
            float fv = __shfl_xor(act[r], 8, 64);
            float gv = __shfl_xor(act[r], 16, 64);
            float ov = __shfl_xor(act[r], 24, 64);
            if (gt == 0) {
                float cn = fv * cst[r] + act[r] * gv;
                cst[r] = cn;
                float hv = ov * tanh_fast(cn);
                float hv2 = __shfl_xor(hv, 1, 64);
                if ((jj & 1) == 0) {
                    uint32_t lo = (uint32_t)__builtin_bit_cast(uint16_t, (bf16_t)hv);
                    uint32_t hi = (uint32_t)__builtin_bit_cast(uint16_t, (bf16_t)hv2);
                    st_u32_llc(hn + wbase + (rrow[r] << 2), lo | (hi << 16));
                }
                if (t == S_DIM - 1) {
                    int rowg = bh * 32 + rrow[r];
                    int j = q * 8 + jj;
                    out[rowg * H_DIM + j] = ov * tanh_fast(cn);   // h_T
                    out[65536 + rowg * H_DIM + j] = cn;           // c_T
                }
            }
        }

        if (tl < CHUNK - 1) {
            unsigned tv = (unsigned)(t + 1);
            // Drain write-through h stores to LLC before signaling.
            asm volatile("s_waitcnt vmcnt(0)" ::: "memory");
            __hip_atomic_store(&flags[wg], tv, __ATOMIC_RELAXED, __HIP_MEMORY_SCOPE_AGENT);
            // xp prefetch for next step issues during the spin (HBM latency hidden).
            #pragma unroll
            for (int r = 0; r < 16; ++r)
                xpr[r] = xp[(size_t)((tl + 1) * 64 + bh * 32 + rrow[r]) * G4 + q * 32 + col];
            int guard = 200000;
            for (;;) {
                unsigned f0 = __hip_atomic_load(&flags[lane],       __ATOMIC_RELAXED, __HIP_MEMORY_SCOPE_AGENT);
                unsigned f1 = __hip_atomic_load(&flags[lane + 64],  __ATOMIC_RELAXED, __HIP_MEMORY_SCOPE_AGENT);
                unsigned f2 = __hip_atomic_load(&flags[lane + 128], __ATOMIC_RELAXED, __HIP_MEMORY_SCOPE_AGENT);
                unsigned f3 = __hip_atomic_load(&flags[lane + 192], __ATOMIC_RELAXED, __HIP_MEMORY_SCOPE_AGENT);
                int ok = (f0 >= tv) && (f1 >= tv) && (f2 >= tv) && (f3 >= tv);
                if (__all(ok) || --guard == 0) break;
                __builtin_amdgcn_s_sleep(1);
            }
            __builtin_amdgcn_fence(__ATOMIC_ACQUIRE, "wavefront");  // compiler-order only; no cache ops
        }
    }

    // persist c-state for next chunk (cached stores; dispatch-end release flushes)
    if (gt == 0) {
        #pragma unroll
        for (int r = 0; r < 16; ++r)
            cstbuf[(bh * 32 + rrow[r]) * H_DIM + q * 8 + jj] = cst[r];
    }
}

extern "C" void kernel_launch(void* const* d_in, const int* in_sizes, int n_in,
                              void* d_out, int out_size, void* d_ws, size_t ws_size,
                              hipStream_t stream) {
    const float* x   = (const float*)d_in[0];
    const float* wii = (const float*)d_in[1];
    const float* bii = (const float*)d_in[2];
    const float* whi = (const float*)d_in[3];
    const float* bhi = (const float*)d_in[4];
    const float* wif = (const float*)d_in[5];
    const float* bif = (const float*)d_in[6];
    const float* whf = (const float*)d_in[7];
    const float* bhf = (const float*)d_in[8];
    const float* wig = (const float*)d_in[9];
    const float* big = (const float*)d_in[10];
    const float* whg = (const float*)d_in[11];
    const float* bhg = (const float*)d_in[12];
    const float* wio = (const float*)d_in[13];
    const float* bio = (const float*)d_in[14];
    const float* who = (const float*)d_in[15];
    const float* bho = (const float*)d_in[16];

    char* ws = (char*)d_ws;
    bf16_t*  wxt   = (bf16_t*)(ws + O_WXT);
    bf16_t*  wht   = (bf16_t*)(ws + O_WHT);
    float*   bias  = (float*)(ws + O_BIAS);
    float*   cstb  = (float*)(ws + O_CST);
    unsigned* flags = (unsigned*)(ws + O_FLAGS);
    bf16_t*  hbuf  = (bf16_t*)(ws + O_HBUF);
    bf16_t*  xp    = (bf16_t*)(ws + O_XP);

    hipMemsetAsync(hbuf, 0, 128 * 1024, stream);           // h0 = 0 (ring slot 0)
    hipMemsetAsync(flags, 0, 256 * sizeof(unsigned), stream);

    k_pack_wx<<<8192, 256, 0, stream>>>(wii, wif, wig, wio, wxt);
    k_pack_wh<<<16384, 256, 0, stream>>>(whi, whf, whg, who, wht);
    k_pack_bias<<<16, 256, 0, stream>>>(bii, bhi, bif, bhf, big, bhg, bio, bho, bias);

    for (int c = 0; c < NCHUNK; ++c) {
        k_xproj<<<dim3(32, CHUNK * 64 / 128), 256, 0, stream>>>(x, wxt, bias, xp, c * CHUNK * 64);
        k_lstm<<<256, 64, 0, stream>>>(wht, xp, hbuf, cstb, (float*)d_out, flags, c * CHUNK);
    }
}

// Round 5
// 7745.984 us; speedup vs baseline: 1.1230x; 1.1230x over previous
//
#include <hip/hip_runtime.h>
#include <hip/hip_bf16.h>
#include <stdint.h>

typedef __bf16 bf16_t;
typedef bf16_t bf16x8 __attribute__((ext_vector_type(8)));
typedef float  f32x4  __attribute__((ext_vector_type(4)));
typedef float  f32x16 __attribute__((ext_vector_type(16)));

#define I_DIM 512
#define H_DIM 1024
#define B_DIM 64
#define S_DIM 512
#define G4    4096   // 4*H
#define CHUNK 32     // steps per chunk
#define NCHUNK (S_DIM / CHUNK)

// ---------------- workspace layout (bytes) — total ~34 MB ----------------
#define O_WXT   0x0000000ULL  // [4096][512]  bf16 = 4 MB
#define O_WHT   0x0400000ULL  // [4096][1024] bf16 = 8 MB
#define O_BIAS  0x0C00000ULL  // [4096] f32 = 16 KB
#define O_CST   0x0C10000ULL  // [64][1024] f32 = 256 KB
#define O_FLAGS 0x0C50000ULL  // 256 arrival flags, 16B-spaced = 4 KB
#define O_MAIL  0x0C60000ULL  // 256 mailboxes, 64B-spaced = 16 KB
#define O_HBUF  0x0D00000ULL  // 33 ring buffers * 128 KB (A-frag order) = 4.125 MB
#define O_XP    0x1200000ULL  // [CHUNK*64][4096] bf16 = 16 MB

__device__ __forceinline__ float sigm(float x)      { return 1.f / (1.f + __expf(-x)); }
__device__ __forceinline__ float tanh_fast(float x) { return 1.f - 2.f / (__expf(2.f * x) + 1.f); }

// Write-through u32 store (sc0 sc1): lands in LLC, no wbl2 needed.
__device__ __forceinline__ void st_u32_llc(uint32_t* p, uint32_t v) {
    __hip_atomic_store(p, v, __ATOMIC_RELAXED, __HIP_MEMORY_SCOPE_AGENT);
}
__device__ __forceinline__ uint32_t ld_u32_llc(const uint32_t* p) {
    return __hip_atomic_load(p, __ATOMIC_RELAXED, __HIP_MEMORY_SCOPE_AGENT);
}

// Packed gate-column permutation: packed col p = q*32 + g*8 + jj  <->  hidden j = q*8+jj, gate g (0:i 1:f 2:g 3:o)

__global__ void k_pack_wx(const float* __restrict__ w0, const float* __restrict__ w1,
                          const float* __restrict__ w2, const float* __restrict__ w3,
                          bf16_t* __restrict__ wxt) {
    int tid = blockIdx.x * 256 + threadIdx.x;
    int k = tid >> 12;
    int p = tid & 4095;
    int q = p >> 5, g = (p >> 3) & 3, jj = p & 7;
    int j = q * 8 + jj;
    const float* src = (g == 0) ? w0 : (g == 1) ? w1 : (g == 2) ? w2 : w3;
    wxt[(size_t)p * I_DIM + k] = (bf16_t)src[k * H_DIM + j];
}

__global__ void k_pack_wh(const float* __restrict__ w0, const float* __restrict__ w1,
                          const float* __restrict__ w2, const float* __restrict__ w3,
                          bf16_t* __restrict__ wht) {
    int tid = blockIdx.x * 256 + threadIdx.x;
    int k = tid >> 12;
    int p = tid & 4095;
    int q = p >> 5, g = (p >> 3) & 3, jj = p & 7;
    int j = q * 8 + jj;
    const float* src = (g == 0) ? w0 : (g == 1) ? w1 : (g == 2) ? w2 : w3;
    wht[(size_t)p * H_DIM + k] = (bf16_t)src[k * H_DIM + j];
}

__global__ void k_pack_bias(const float* bi0, const float* bh0, const float* bi1, const float* bh1,
                            const float* bi2, const float* bh2, const float* bi3, const float* bh3,
                            float* __restrict__ bias) {
    int p = blockIdx.x * 256 + threadIdx.x;
    int q = p >> 5, g = (p >> 3) & 3, jj = p & 7;
    int j = q * 8 + jj;
    const float* a = (g == 0) ? bi0 : (g == 1) ? bi1 : (g == 2) ? bi2 : bi3;
    const float* b = (g == 0) ? bh0 : (g == 1) ? bh1 : (g == 2) ? bh2 : bh3;
    bias[p] = a[j] + b[j];
}

// ---------------- chunked x_proj GEMM ----------------
__global__ __launch_bounds__(256, 2) void k_xproj(
    const float* __restrict__ x, const bf16_t* __restrict__ wxt,
    const float* __restrict__ bias, bf16_t* __restrict__ xp, int r_base)
{
    __shared__ __align__(16) bf16_t Al[8 * 64 * 8];
    __shared__ __align__(16) bf16_t Bl[8 * 64 * 8];
    const int tid = threadIdx.x;
    const int n0 = blockIdx.x * 128;
    const int r0 = r_base + blockIdx.y * 128;
    const int wv = tid >> 6;
    const int lane = tid & 63;
    const int mq = wv >> 1, nq = wv & 1;
    f32x4 acc[4][4] = {};

    for (int kk = 0; kk < I_DIM; kk += 32) {
        __syncthreads();
        #pragma unroll
        for (int sidx = 0; sidx < 2; ++sidx) {
            int s = tid + sidx * 256;
            int mt = s >> 6, l = s & 63;
            int m = l & 15, kb = (l >> 4) * 8;
            int r = r0 + mt * 16 + m;
            int b = r & 63, si = r >> 6;
            const float* gp = x + ((size_t)(b * S_DIM + si)) * I_DIM + kk + kb;
            float4 v0 = *(const float4*)gp;
            float4 v1 = *(const float4*)(gp + 4);
            bf16x8 a;
            a[0] = (bf16_t)v0.x; a[1] = (bf16_t)v0.y; a[2] = (bf16_t)v0.z; a[3] = (bf16_t)v0.w;
            a[4] = (bf16_t)v1.x; a[5] = (bf16_t)v1.y; a[6] = (bf16_t)v1.z; a[7] = (bf16_t)v1.w;
            *(bf16x8*)&Al[s * 8] = a;
            bf16x8 bv = *(const bf16x8*)(wxt + (size_t)(n0 + mt * 16 + m) * I_DIM + kk + kb);
            *(bf16x8*)&Bl[s * 8] = bv;
        }
        __syncthreads();
        bf16x8 af[4], bfr[4];
        #pragma unroll
        for (int mt = 0; mt < 4; ++mt) af[mt]  = *(bf16x8*)&Al[((mq * 4 + mt) * 64 + lane) * 8];
        #pragma unroll
        for (int nt = 0; nt < 4; ++nt) bfr[nt] = *(bf16x8*)&Bl[((nq * 4 + nt) * 64 + lane) * 8];
        #pragma unroll
        for (int mt = 0; mt < 4; ++mt)
            #pragma unroll
            for (int nt = 0; nt < 4; ++nt)
                acc[mt][nt] = __builtin_amdgcn_mfma_f32_16x16x32_bf16(af[mt], bfr[nt], acc[mt][nt], 0, 0, 0);
    }
    const int l15 = lane & 15, quad = lane >> 4;
    #pragma unroll
    for (int nt = 0; nt < 4; ++nt) {
        int col = n0 + nq * 64 + nt * 16 + l15;
        float bv = bias[col];
        #pragma unroll
        for (int mt = 0; mt < 4; ++mt)
            #pragma unroll
            for (int r = 0; r < 4; ++r) {
                int row = r0 - r_base + mq * 64 + mt * 16 + quad * 4 + r;
                xp[(size_t)row * G4 + col] = (bf16_t)(acc[mt][nt][r] + bv);
            }
    }
}

// ---------------- persistent recurrent kernel (one chunk of CHUNK steps) ----------------
// Grid = 258 WGs x 64 thr:
//   wg 0..255   workers: q = wg&127 (8 hidden units = 32 packed cols), bh = wg>>7 (batch half).
//   wg 256,257  aggregators, one per batch half.
// The two batch halves are INDEPENDENT recurrences (WG (q,bh) reads/writes only
// rows of half bh) -> two disjoint 128-WG barrier domains.
// Barrier (per half): worker drains h stores (vmcnt0), write-through flag ->
// aggregator (sole reader) polls 128 flags, publishes epoch to 128 PRIVATE
// 64B-spaced mailboxes -> each worker polls only its own line (1 reader/line).
// This kills the R2-R4 wall (~15 us/step): 256 waves all-poll-all on 16 shared
// flag lines serialized at the LLC (~5 us per contended poll round).
__global__ __launch_bounds__(64, 1) void k_lstm(
    const bf16_t* __restrict__ wht, const bf16_t* __restrict__ xp,
    bf16_t* __restrict__ hbuf, float* __restrict__ cstbuf,
    float* __restrict__ out, unsigned* __restrict__ flags,
    unsigned* __restrict__ mail, int t0)
{
    __shared__ __align__(16) bf16_t Blds[32768];   // 64 KB B-fragments [ks(64)][lane(64)][8]
    const int lane = threadIdx.x;
    const int wg = blockIdx.x;

    if (wg >= 256) {
        // ---- aggregator for batch half a ----
        const int a = wg - 256;
        unsigned* fl = flags + (size_t)a * 512;   // 128 slots, 16B-spaced (4 u32)
        unsigned* ml = mail  + (size_t)a * 2048;  // 128 slots, 64B-spaced (16 u32)
        for (int tl = 0; tl + 1 < CHUNK; ++tl) {
            unsigned tv = (unsigned)(t0 + tl + 1);
            int guard = 2000000;
            for (;;) {
                unsigned f0 = ld_u32_llc(fl + lane * 4);
                unsigned f1 = ld_u32_llc(fl + (lane + 64) * 4);
                int ok = (f0 >= tv) && (f1 >= tv);
                if (__all(ok) || --guard == 0) break;
                __builtin_amdgcn_s_sleep(1);
            }
            st_u32_llc(ml + lane * 16, tv);
            st_u32_llc(ml + (lane + 64) * 16, tv);
        }
        return;
    }

    const int q  = wg & 127;
    const int bh = wg >> 7;

    // Stage WhT rows q*32..+31 into LDS in 32x32x16 B-fragment order.
    for (int i = 0; i < 64; ++i) {
        int task = lane + (i << 6);
        int c = task >> 7;
        int k = (task & 127) << 3;
        bf16x8 v = *(const bf16x8*)(wht + (((size_t)(q * 32 + c)) << 10) + k);
        int base = (((k >> 4) << 6) + c + (((k >> 3) & 1) << 5)) << 3;
        *(bf16x8*)&Blds[base] = v;
    }
    __syncthreads();

    const int col  = lane & 31;
    const int ksel = lane >> 5;
    const int gt   = (lane >> 3) & 3;  // 0:i 1:f 2:g 3:o
    const int jj   = lane & 7;

    int rrow[16];
    #pragma unroll
    for (int r = 0; r < 16; ++r) rrow[r] = (r & 3) + 8 * (r >> 2) + 4 * ksel;

    float cst[16];
    if (t0 == 0) {
        #pragma unroll
        for (int r = 0; r < 16; ++r) cst[r] = 0.f;
    } else {
        #pragma unroll
        for (int r = 0; r < 16; ++r)
            cst[r] = cstbuf[(bh * 32 + rrow[r]) * H_DIM + q * 8 + jj];
    }

    bf16_t xpr[16];
    #pragma unroll
    for (int r = 0; r < 16; ++r)
        xpr[r] = xp[(size_t)(bh * 32 + rrow[r]) * G4 + q * 32 + col];

    // writer scatter base (u32 units within a step buffer):
    //   bh*16384 + ((q>>1)*64 + rrow[r] + 32*(q&1))*4 + (jj>>1)
    const int wbase = (bh << 14) + (((q >> 1) << 6) + ((q & 1) << 5)) * 4 + (jj >> 1);
    unsigned* myflag = flags + (size_t)(bh * 128 + q) * 4;
    unsigned* mymail = mail  + (size_t)(bh * 128 + q) * 16;

    for (int tl = 0; tl < CHUNK; ++tl) {
        const int t = t0 + tl;
        const int rd = (tl == 0) ? ((t0 == 0) ? 0 : 32) : tl;
        const bf16_t* ab = hbuf + ((size_t)rd << 16) + (bh << 15) + (lane << 3);

        f32x16 acc0 = {}, acc1 = {}, acc2 = {}, acc3 = {};
        #pragma unroll
        for (int ks = 0; ks < 64; ks += 4) {
            bf16x8 a0 = *(const bf16x8*)(ab + (ks + 0) * 512);
            bf16x8 a1 = *(const bf16x8*)(ab + (ks + 1) * 512);
            bf16x8 a2 = *(const bf16x8*)(ab + (ks + 2) * 512);
            bf16x8 a3 = *(const bf16x8*)(ab + (ks + 3) * 512);
            bf16x8 b0 = *(const bf16x8*)&Blds[(((ks + 0) << 6) + lane) << 3];
            bf16x8 b1 = *(const bf16x8*)&Blds[(((ks + 1) << 6) + lane) << 3];
            bf16x8 b2 = *(const bf16x8*)&Blds[(((ks + 2) << 6) + lane) << 3];
            bf16x8 b3 = *(const bf16x8*)&Blds[(((ks + 3) << 6) + lane) << 3];
            acc0 = __builtin_amdgcn_mfma_f32_32x32x16_bf16(a0, b0, acc0, 0, 0, 0);
            acc1 = __builtin_amdgcn_mfma_f32_32x32x16_bf16(a1, b1, acc1, 0, 0, 0);
            acc2 = __builtin_amdgcn_mfma_f32_32x32x16_bf16(a2, b2, acc2, 0, 0, 0);
            acc3 = __builtin_amdgcn_mfma_f32_32x32x16_bf16(a3, b3, acc3, 0, 0, 0);
        }
        f32x16 accs = acc0 + acc1 + acc2 + acc3;

        float act[16];
        #pragma unroll
        for (int r = 0; r < 16; ++r) {
            float pre = accs[r] + (float)xpr[r];
            act[r] = (gt == 2) ? tanh_fast(pre) : sigm(pre);
        }

        // h update: i-lanes own (row, j); pack bf16 pairs, write-through to buf[tl+1].
        uint32_t* hn = (uint32_t*)hbuf + ((size_t)(tl + 1) << 15);
        #pragma unroll
        for (int r = 0; r < 16; ++r) {
            float fv = __shfl_xor(act[r], 8, 64);
            float gv = __shfl_xor(act[r], 16, 64);
            float ov = __shfl_xor(act[r], 24, 64);
            if (gt == 0) {
                float cn = fv * cst[r] + act[r] * gv;
                cst[r] = cn;
                float hv = ov * tanh_fast(cn);
                float hv2 = __shfl_xor(hv, 1, 64);
                if ((jj & 1) == 0) {
                    uint32_t lo = (uint32_t)__builtin_bit_cast(uint16_t, (bf16_t)hv);
                    uint32_t hi = (uint32_t)__builtin_bit_cast(uint16_t, (bf16_t)hv2);
                    st_u32_llc(hn + wbase + (rrow[r] << 2), lo | (hi << 16));
                }
                if (t == S_DIM - 1) {
                    int rowg = bh * 32 + rrow[r];
                    int j = q * 8 + jj;
                    out[rowg * H_DIM + j] = ov * tanh_fast(cn);   // h_T
                    out[65536 + rowg * H_DIM + j] = cn;           // c_T
                }
            }
        }

        if (tl < CHUNK - 1) {
            unsigned tv = (unsigned)(t + 1);
            // Drain write-through h stores to LLC, then signal arrival.
            asm volatile("s_waitcnt vmcnt(0)" ::: "memory");
            st_u32_llc(myflag, tv);
            // xp prefetch for next step issues during the wait (HBM latency hidden).
            #pragma unroll
            for (int r = 0; r < 16; ++r)
                xpr[r] = xp[(size_t)((tl + 1) * 64 + bh * 32 + rrow[r]) * G4 + q * 32 + col];
            // Poll ONLY our private mailbox line (single reader, zero contention).
            int guard = 1000000;
            for (;;) {
                unsigned m = ld_u32_llc(mymail);
                if (m >= tv || --guard == 0) break;
                __builtin_amdgcn_s_sleep(2);
            }
            __builtin_amdgcn_fence(__ATOMIC_ACQUIRE, "wavefront");  // compiler-order only
        }
    }

    // persist c-state for next chunk
    if (gt == 0) {
        #pragma unroll
        for (int r = 0; r < 16; ++r)
            cstbuf[(bh * 32 + rrow[r]) * H_DIM + q * 8 + jj] = cst[r];
    }
}

extern "C" void kernel_launch(void* const* d_in, const int* in_sizes, int n_in,
                              void* d_out, int out_size, void* d_ws, size_t ws_size,
                              hipStream_t stream) {
    const float* x   = (const float*)d_in[0];
    const float* wii = (const float*)d_in[1];
    const float* bii = (const float*)d_in[2];
    const float* whi = (const float*)d_in[3];
    const float* bhi = (const float*)d_in[4];
    const float* wif = (const float*)d_in[5];
    const float* bif = (const float*)d_in[6];
    const float* whf = (const float*)d_in[7];
    const float* bhf = (const float*)d_in[8];
    const float* wig = (const float*)d_in[9];
    const float* big = (const float*)d_in[10];
    const float* whg = (const float*)d_in[11];
    const float* bhg = (const float*)d_in[12];
    const float* wio = (const float*)d_in[13];
    const float* bio = (const float*)d_in[14];
    const float* who = (const float*)d_in[15];
    const float* bho = (const float*)d_in[16];

    char* ws = (char*)d_ws;
    bf16_t*  wxt   = (bf16_t*)(ws + O_WXT);
    bf16_t*  wht   = (bf16_t*)(ws + O_WHT);
    float*   bias  = (float*)(ws + O_BIAS);
    float*   cstb  = (float*)(ws + O_CST);
    unsigned* flags = (unsigned*)(ws + O_FLAGS);
    unsigned* mail  = (unsigned*)(ws + O_MAIL);
    bf16_t*  hbuf  = (bf16_t*)(ws + O_HBUF);
    bf16_t*  xp    = (bf16_t*)(ws + O_XP);

    hipMemsetAsync(hbuf, 0, 128 * 1024, stream);            // h0 = 0 (ring slot 0)
    hipMemsetAsync(flags, 0, 4096, stream);
    hipMemsetAsync(mail, 0, 16384, stream);

    k_pack_wx<<<8192, 256, 0, stream>>>(wii, wif, wig, wio, wxt);
    k_pack_wh<<<16384, 256, 0, stream>>>(whi, whf, whg, who, wht);
    k_pack_bias<<<16, 256, 0, stream>>>(bii, bhi, bif, bhf, big, bhg, bio, bho, bias);

    for (int c = 0; c < NCHUNK; ++c) {
        k_xproj<<<dim3(32, CHUNK * 64 / 128), 256, 0, stream>>>(x, wxt, bias, xp, c * CHUNK * 64);
        k_lstm<<<258, 64, 0, stream>>>(wht, xp, hbuf, cstb, (float*)d_out, flags, mail, c * CHUNK);
    }
}

// Round 6
// 7256.447 us; speedup vs baseline: 1.1987x; 1.0675x over previous
//
#include <hip/hip_runtime.h>
#include <hip/hip_bf16.h>
#include <stdint.h>

typedef __bf16 bf16_t;
typedef bf16_t bf16x8 __attribute__((ext_vector_type(8)));
typedef float  f32x4  __attribute__((ext_vector_type(4)));
typedef float  f32x16 __attribute__((ext_vector_type(16)));

#define I_DIM 512
#define H_DIM 1024
#define B_DIM 64
#define S_DIM 512
#define G4    4096   // 4*H
#define CHUNK 32     // steps per chunk
#define NCHUNK (S_DIM / CHUNK)

// ---------------- workspace layout (bytes) — total ~34 MB ----------------
#define O_WXT   0x0000000ULL  // [4096][512]  bf16 = 4 MB
#define O_WHT   0x0400000ULL  // [4096][1024] bf16 = 8 MB
#define O_BIAS  0x0C00000ULL  // [4096] f32 = 16 KB
#define O_CST   0x0C10000ULL  // [64][1024] f32 = 256 KB
#define O_FLAGS 0x0C50000ULL  // 256 arrival flags, 16B-spaced = 4 KB
#define O_MAIL  0x0C60000ULL  // 256 mailboxes, 64B-spaced = 16 KB
#define O_HBUF  0x0D00000ULL  // 33 ring buffers * 128 KB (A-frag order) = 4.125 MB
#define O_XP    0x1200000ULL  // [CHUNK*64][4096] bf16 = 16 MB

__device__ __forceinline__ float sigm(float x)      { return 1.f / (1.f + __expf(-x)); }
__device__ __forceinline__ float tanh_fast(float x) { return 1.f - 2.f / (__expf(2.f * x) + 1.f); }

// Write-through stores / bypass loads (sc0 sc1): individually LLC-coherent.
__device__ __forceinline__ void st_u32_llc(uint32_t* p, uint32_t v) {
    __hip_atomic_store(p, v, __ATOMIC_RELAXED, __HIP_MEMORY_SCOPE_AGENT);
}
__device__ __forceinline__ void st_u64_llc(uint64_t* p, uint64_t v) {
    __hip_atomic_store(p, v, __ATOMIC_RELAXED, __HIP_MEMORY_SCOPE_AGENT);
}
__device__ __forceinline__ uint32_t ld_u32_llc(const uint32_t* p) {
    return __hip_atomic_load(p, __ATOMIC_RELAXED, __HIP_MEMORY_SCOPE_AGENT);
}

// Packed gate-column permutation: packed col p = q*32 + g*8 + jj  <->  hidden j = q*8+jj, gate g (0:i 1:f 2:g 3:o)

__global__ void k_pack_wx(const float* __restrict__ w0, const float* __restrict__ w1,
                          const float* __restrict__ w2, const float* __restrict__ w3,
                          bf16_t* __restrict__ wxt) {
    int tid = blockIdx.x * 256 + threadIdx.x;
    int k = tid >> 12;
    int p = tid & 4095;
    int q = p >> 5, g = (p >> 3) & 3, jj = p & 7;
    int j = q * 8 + jj;
    const float* src = (g == 0) ? w0 : (g == 1) ? w1 : (g == 2) ? w2 : w3;
    wxt[(size_t)p * I_DIM + k] = (bf16_t)src[k * H_DIM + j];
}

__global__ void k_pack_wh(const float* __restrict__ w0, const float* __restrict__ w1,
                          const float* __restrict__ w2, const float* __restrict__ w3,
                          bf16_t* __restrict__ wht) {
    int tid = blockIdx.x * 256 + threadIdx.x;
    int k = tid >> 12;
    int p = tid & 4095;
    int q = p >> 5, g = (p >> 3) & 3, jj = p & 7;
    int j = q * 8 + jj;
    const float* src = (g == 0) ? w0 : (g == 1) ? w1 : (g == 2) ? w2 : w3;
    wht[(size_t)p * H_DIM + k] = (bf16_t)src[k * H_DIM + j];
}

__global__ void k_pack_bias(const float* bi0, const float* bh0, const float* bi1, const float* bh1,
                            const float* bi2, const float* bh2, const float* bi3, const float* bh3,
                            float* __restrict__ bias) {
    int p = blockIdx.x * 256 + threadIdx.x;
    int q = p >> 5, g = (p >> 3) & 3, jj = p & 7;
    int j = q * 8 + jj;
    const float* a = (g == 0) ? bi0 : (g == 1) ? bi1 : (g == 2) ? bi2 : bi3;
    const float* b = (g == 0) ? bh0 : (g == 1) ? bh1 : (g == 2) ? bh2 : bh3;
    bias[p] = a[j] + b[j];
}

// ---------------- chunked x_proj GEMM ----------------
__global__ __launch_bounds__(256, 2) void k_xproj(
    const float* __restrict__ x, const bf16_t* __restrict__ wxt,
    const float* __restrict__ bias, bf16_t* __restrict__ xp, int r_base)
{
    __shared__ __align__(16) bf16_t Al[8 * 64 * 8];
    __shared__ __align__(16) bf16_t Bl[8 * 64 * 8];
    const int tid = threadIdx.x;
    const int n0 = blockIdx.x * 128;
    const int r0 = r_base + blockIdx.y * 128;
    const int wv = tid >> 6;
    const int lane = tid & 63;
    const int mq = wv >> 1, nq = wv & 1;
    f32x4 acc[4][4] = {};

    for (int kk = 0; kk < I_DIM; kk += 32) {
        __syncthreads();
        #pragma unroll
        for (int sidx = 0; sidx < 2; ++sidx) {
            int s = tid + sidx * 256;
            int mt = s >> 6, l = s & 63;
            int m = l & 15, kb = (l >> 4) * 8;
            int r = r0 + mt * 16 + m;
            int b = r & 63, si = r >> 6;
            const float* gp = x + ((size_t)(b * S_DIM + si)) * I_DIM + kk + kb;
            float4 v0 = *(const float4*)gp;
            float4 v1 = *(const float4*)(gp + 4);
            bf16x8 a;
            a[0] = (bf16_t)v0.x; a[1] = (bf16_t)v0.y; a[2] = (bf16_t)v0.z; a[3] = (bf16_t)v0.w;
            a[4] = (bf16_t)v1.x; a[5] = (bf16_t)v1.y; a[6] = (bf16_t)v1.z; a[7] = (bf16_t)v1.w;
            *(bf16x8*)&Al[s * 8] = a;
            bf16x8 bv = *(const bf16x8*)(wxt + (size_t)(n0 + mt * 16 + m) * I_DIM + kk + kb);
            *(bf16x8*)&Bl[s * 8] = bv;
        }
        __syncthreads();
        bf16x8 af[4], bfr[4];
        #pragma unroll
        for (int mt = 0; mt < 4; ++mt) af[mt]  = *(bf16x8*)&Al[((mq * 4 + mt) * 64 + lane) * 8];
        #pragma unroll
        for (int nt = 0; nt < 4; ++nt) bfr[nt] = *(bf16x8*)&Bl[((nq * 4 + nt) * 64 + lane) * 8];
        #pragma unroll
        for (int mt = 0; mt < 4; ++mt)
            #pragma unroll
            for (int nt = 0; nt < 4; ++nt)
                acc[mt][nt] = __builtin_amdgcn_mfma_f32_16x16x32_bf16(af[mt], bfr[nt], acc[mt][nt], 0, 0, 0);
    }
    const int l15 = lane & 15, quad = lane >> 4;
    #pragma unroll
    for (int nt = 0; nt < 4; ++nt) {
        int col = n0 + nq * 64 + nt * 16 + l15;
        float bv = bias[col];
        #pragma unroll
        for (int mt = 0; mt < 4; ++mt)
            #pragma unroll
            for (int r = 0; r < 4; ++r) {
                int row = r0 - r_base + mq * 64 + mt * 16 + quad * 4 + r;
                xp[(size_t)row * G4 + col] = (bf16_t)(acc[mt][nt][r] + bv);
            }
    }
}

// ---------------- persistent recurrent kernel (one chunk of CHUNK steps) ----------------
// Grid = 258 WGs x 64 thr: wg 0..255 workers (q = wg&127, bh = wg>>7),
// wg 256/257 = per-half aggregators (two independent 128-WG barrier domains).
// R6 changes vs R5 (both attack the worker's serial step path):
//  (1) 8-deep software-pipelined A-loads: rotating register window, loads
//      issued 8 iterations ahead -> residual stall ~ latency/8 (was: 16
//      load->MFMA dependency groups each eating ~700cyc LLC latency).
//  (2) h output of a WG is ONE contiguous 512B block in A-frag layout:
//      redistribute through LDS, emit a single global_store_dwordx2 sc0sc1
//      per wave -> vmcnt(0) drain = 1 ack RT (was: 16 scattered write-through
//      stores drained serially).
__global__ __launch_bounds__(64, 1) void k_lstm(
    const bf16_t* __restrict__ wht, const bf16_t* __restrict__ xp,
    bf16_t* __restrict__ hbuf, float* __restrict__ cstbuf,
    float* __restrict__ out, unsigned* __restrict__ flags,
    unsigned* __restrict__ mail, int t0)
{
    __shared__ __align__(16) bf16_t Blds[32768];   // 64 KB B-fragments [ks(64)][lane(64)][8]
    __shared__ __align__(16) bf16_t Hlds[256];     // 512 B h-redistribute scratch
    const int lane = threadIdx.x;
    const int wg = blockIdx.x;

    if (wg >= 256) {
        // ---- aggregator for batch half a ----
        const int a = wg - 256;
        unsigned* fl = flags + (size_t)a * 512;   // 128 slots, 16B-spaced
        unsigned* ml = mail  + (size_t)a * 2048;  // 128 slots, 64B-spaced
        for (int tl = 0; tl + 1 < CHUNK; ++tl) {
            unsigned tv = (unsigned)(t0 + tl + 1);
            int guard = 2000000;
            for (;;) {
                unsigned f0 = ld_u32_llc(fl + lane * 4);
                unsigned f1 = ld_u32_llc(fl + (lane + 64) * 4);
                int ok = (f0 >= tv) && (f1 >= tv);
                if (__all(ok) || --guard == 0) break;
                __builtin_amdgcn_s_sleep(1);
            }
            st_u32_llc(ml + lane * 16, tv);
            st_u32_llc(ml + (lane + 64) * 16, tv);
        }
        return;
    }

    const int q  = wg & 127;
    const int bh = wg >> 7;

    // Stage WhT rows q*32..+31 into LDS in 32x32x16 B-fragment order.
    for (int i = 0; i < 64; ++i) {
        int task = lane + (i << 6);
        int c = task >> 7;
        int k = (task & 127) << 3;
        bf16x8 v = *(const bf16x8*)(wht + (((size_t)(q * 32 + c)) << 10) + k);
        int base = (((k >> 4) << 6) + c + (((k >> 3) & 1) << 5)) << 3;
        *(bf16x8*)&Blds[base] = v;
    }
    __syncthreads();

    const int col  = lane & 31;
    const int ksel = lane >> 5;
    const int gt   = (lane >> 3) & 3;  // 0:i 1:f 2:g 3:o
    const int jj   = lane & 7;

    int rrow[16];
    #pragma unroll
    for (int r = 0; r < 16; ++r) rrow[r] = (r & 3) + 8 * (r >> 2) + 4 * ksel;

    float cst[16];
    if (t0 == 0) {
        #pragma unroll
        for (int r = 0; r < 16; ++r) cst[r] = 0.f;
    } else {
        #pragma unroll
        for (int r = 0; r < 16; ++r)
            cst[r] = cstbuf[(bh * 32 + rrow[r]) * H_DIM + q * 8 + jj];
    }

    bf16_t xpr[16];
    #pragma unroll
    for (int r = 0; r < 16; ++r)
        xpr[r] = xp[(size_t)(bh * 32 + rrow[r]) * G4 + q * 32 + col];

    // WG's h-output block (contiguous 512 B) in u64 units within a step buffer:
    const int hw_off = (bh << 13) + ((q >> 1) << 7) + ((q & 1) << 6) + lane;
    unsigned* myflag = flags + (size_t)(bh * 128 + q) * 4;
    unsigned* mymail = mail  + (size_t)(bh * 128 + q) * 16;

    for (int tl = 0; tl < CHUNK; ++tl) {
        const int t = t0 + tl;
        const int rd = (tl == 0) ? ((t0 == 0) ? 0 : 32) : tl;
        const bf16_t* ab = hbuf + ((size_t)rd << 16) + (bh << 15) + (lane << 3);

        // 8-deep pipelined A-loads + MFMA (4 independent accumulator chains).
        bf16x8 afr[8];
        #pragma unroll
        for (int i = 0; i < 8; ++i) afr[i] = *(const bf16x8*)(ab + i * 512);
        f32x16 acc0 = {}, acc1 = {}, acc2 = {}, acc3 = {};
        #pragma unroll
        for (int ks = 0; ks < 64; ++ks) {
            bf16x8 a = afr[ks & 7];
            if (ks < 56) afr[ks & 7] = *(const bf16x8*)(ab + (ks + 8) * 512);
            bf16x8 b = *(const bf16x8*)&Blds[((ks << 6) + lane) << 3];
            if ((ks & 3) == 0)      acc0 = __builtin_amdgcn_mfma_f32_32x32x16_bf16(a, b, acc0, 0, 0, 0);
            else if ((ks & 3) == 1) acc1 = __builtin_amdgcn_mfma_f32_32x32x16_bf16(a, b, acc1, 0, 0, 0);
            else if ((ks & 3) == 2) acc2 = __builtin_amdgcn_mfma_f32_32x32x16_bf16(a, b, acc2, 0, 0, 0);
            else                    acc3 = __builtin_amdgcn_mfma_f32_32x32x16_bf16(a, b, acc3, 0, 0, 0);
        }
        f32x16 accs = acc0 + acc1 + acc2 + acc3;

        float act[16];
        #pragma unroll
        for (int r = 0; r < 16; ++r) {
            float pre = accs[r] + (float)xpr[r];
            act[r] = (gt == 2) ? tanh_fast(pre) : sigm(pre);
        }

        // c/h update on i-lanes; h values go to LDS for coalesced store.
        #pragma unroll
        for (int r = 0; r < 16; ++r) {
            float fv = __shfl_xor(act[r], 8, 64);
            float gv = __shfl_xor(act[r], 16, 64);
            float ov = __shfl_xor(act[r], 24, 64);
            if (gt == 0) {
                float cn = fv * cst[r] + act[r] * gv;
                cst[r] = cn;
                float hv = ov * tanh_fast(cn);
                Hlds[rrow[r] * 8 + jj] = (bf16_t)hv;
                if (t == S_DIM - 1) {
                    int rowg = bh * 32 + rrow[r];
                    int j = q * 8 + jj;
                    out[rowg * H_DIM + j] = hv;            // h_T
                    out[65536 + rowg * H_DIM + j] = cn;    // c_T
                }
            }
        }
        asm volatile("s_waitcnt lgkmcnt(0)" ::: "memory");  // single wave: ds_write -> ds_read order

        // ONE coalesced write-through store per wave: 64 lanes x 8 B = 512 B.
        {
            uint64_t v = *(const uint64_t*)&Hlds[lane * 4];
            uint64_t* hwn = (uint64_t*)hbuf + ((size_t)(tl + 1) << 14) + hw_off;
            st_u64_llc(hwn, v);
        }

        if (tl < CHUNK - 1) {
            unsigned tv = (unsigned)(t + 1);
            // Drain the single h store to LLC, then signal arrival.
            asm volatile("s_waitcnt vmcnt(0)" ::: "memory");
            st_u32_llc(myflag, tv);
            // xp prefetch for next step issues during the wait.
            #pragma unroll
            for (int r = 0; r < 16; ++r)
                xpr[r] = xp[(size_t)((tl + 1) * 64 + bh * 32 + rrow[r]) * G4 + q * 32 + col];
            // Poll only our private mailbox line (single reader, no contention).
            int guard = 1000000;
            for (;;) {
                unsigned m = ld_u32_llc(mymail);
                if (m >= tv || --guard == 0) break;
                __builtin_amdgcn_s_sleep(1);
            }
            __builtin_amdgcn_fence(__ATOMIC_ACQUIRE, "wavefront");  // compiler-order only
        }
    }

    // persist c-state for next chunk
    if (gt == 0) {
        #pragma unroll
        for (int r = 0; r < 16; ++r)
            cstbuf[(bh * 32 + rrow[r]) * H_DIM + q * 8 + jj] = cst[r];
    }
}

extern "C" void kernel_launch(void* const* d_in, const int* in_sizes, int n_in,
                              void* d_out, int out_size, void* d_ws, size_t ws_size,
                              hipStream_t stream) {
    const float* x   = (const float*)d_in[0];
    const float* wii = (const float*)d_in[1];
    const float* bii = (const float*)d_in[2];
    const float* whi = (const float*)d_in[3];
    const float* bhi = (const float*)d_in[4];
    const float* wif = (const float*)d_in[5];
    const float* bif = (const float*)d_in[6];
    const float* whf = (const float*)d_in[7];
    const float* bhf = (const float*)d_in[8];
    const float* wig = (const float*)d_in[9];
    const float* big = (const float*)d_in[10];
    const float* whg = (const float*)d_in[11];
    const float* bhg = (const float*)d_in[12];
    const float* wio = (const float*)d_in[13];
    const float* bio = (const float*)d_in[14];
    const float* who = (const float*)d_in[15];
    const float* bho = (const float*)d_in[16];

    char* ws = (char*)d_ws;
    bf16_t*  wxt   = (bf16_t*)(ws + O_WXT);
    bf16_t*  wht   = (bf16_t*)(ws + O_WHT);
    float*   bias  = (float*)(ws + O_BIAS);
    float*   cstb  = (float*)(ws + O_CST);
    unsigned* flags = (unsigned*)(ws + O_FLAGS);
    unsigned* mail  = (unsigned*)(ws + O_MAIL);
    bf16_t*  hbuf  = (bf16_t*)(ws + O_HBUF);
    bf16_t*  xp    = (bf16_t*)(ws + O_XP);

    hipMemsetAsync(hbuf, 0, 128 * 1024, stream);            // h0 = 0 (ring slot 0)
    hipMemsetAsync(flags, 0, 4096, stream);
    hipMemsetAsync(mail, 0, 16384, stream);

    k_pack_wx<<<8192, 256, 0, stream>>>(wii, wif, wig, wio, wxt);
    k_pack_wh<<<16384, 256, 0, stream>>>(whi, whf, whg, who, wht);
    k_pack_bias<<<16, 256, 0, stream>>>(bii, bhi, bif, bhf, big, bhg, bio, bho, bias);

    for (int c = 0; c < NCHUNK; ++c) {
        k_xproj<<<dim3(32, CHUNK * 64 / 128), 256, 0, stream>>>(x, wxt, bias, xp, c * CHUNK * 64);
        k_lstm<<<258, 64, 0, stream>>>(wht, xp, hbuf, cstb, (float*)d_out, flags, mail, c * CHUNK);
    }
}

// Round 7
// 5604.479 us; speedup vs baseline: 1.5521x; 1.2948x over previous
//
#include <hip/hip_runtime.h>
#include <hip/hip_bf16.h>
#include <stdint.h>

typedef __bf16 bf16_t;
typedef bf16_t bf16x8 __attribute__((ext_vector_type(8)));
typedef float  f32x4  __attribute__((ext_vector_type(4)));
typedef float  f32x16 __attribute__((ext_vector_type(16)));

#define I_DIM 512
#define H_DIM 1024
#define B_DIM 64
#define S_DIM 512
#define G4    4096   // 4*H
#define CHUNK 32     // xproj steps per chunk
#define NCHUNK (S_DIM / CHUNK)

// ---------------- workspace layout (bytes) — total ~34 MB ----------------
#define O_WXT   0x0000000ULL  // [4096][512]  bf16 = 4 MB   (packed WxT, row-major)
#define O_WHTF  0x0400000ULL  // [128][64][64][8] bf16 = 8 MB (Wh in MFMA B-frag order)
#define O_BIAS  0x0C00000ULL  // [4096] f32 = 16 KB
#define O_CST   0x0C10000ULL  // [64][1024] f32 = 256 KB (c-state, address-stable)
#define O_HBUF  0x0D00000ULL  // 2 slots * 128 KB (h in A-frag order) = 256 KB
#define O_XP    0x1200000ULL  // [CHUNK*64][4096] bf16 = 16 MB

__device__ __forceinline__ float sigm(float x)      { return 1.f / (1.f + __expf(-x)); }
__device__ __forceinline__ float tanh_fast(float x) { return 1.f - 2.f / (__expf(2.f * x) + 1.f); }

// Packed gate-column permutation: packed col p = q*32 + g*8 + jj  <->  hidden j = q*8+jj, gate g (0:i 1:f 2:g 3:o)

__global__ void k_pack_wx(const float* __restrict__ w0, const float* __restrict__ w1,
                          const float* __restrict__ w2, const float* __restrict__ w3,
                          bf16_t* __restrict__ wxt) {
    int tid = blockIdx.x * 256 + threadIdx.x;
    int k = tid >> 12;
    int p = tid & 4095;
    int q = p >> 5, g = (p >> 3) & 3, jj = p & 7;
    int j = q * 8 + jj;
    const float* src = (g == 0) ? w0 : (g == 1) ? w1 : (g == 2) ? w2 : w3;
    wxt[(size_t)p * I_DIM + k] = (bf16_t)src[k * H_DIM + j];
}

// Wh -> global MFMA B-fragment order: whtf[q][ks][lane][8]
//   element = WhT[p = q*32 + (lane&31)][k = ks*16 + (lane>>5)*8 + e]
__global__ void k_pack_whf(const float* __restrict__ w0, const float* __restrict__ w1,
                           const float* __restrict__ w2, const float* __restrict__ w3,
                           bf16_t* __restrict__ whtf) {
    int idx = blockIdx.x * 256 + threadIdx.x;     // 0..4194303
    int e    = idx & 7;
    int lane = (idx >> 3) & 63;
    int ks   = (idx >> 9) & 63;
    int q    = idx >> 15;                          // 0..127
    int k = ks * 16 + (lane >> 5) * 8 + e;
    int c = lane & 31;
    int g = c >> 3, jj = c & 7;
    int j = q * 8 + jj;
    const float* src = (g == 0) ? w0 : (g == 1) ? w1 : (g == 2) ? w2 : w3;
    whtf[idx] = (bf16_t)src[k * H_DIM + j];
}

__global__ void k_pack_bias(const float* bi0, const float* bh0, const float* bi1, const float* bh1,
                            const float* bi2, const float* bh2, const float* bi3, const float* bh3,
                            float* __restrict__ bias) {
    int p = blockIdx.x * 256 + threadIdx.x;
    int q = p >> 5, g = (p >> 3) & 3, jj = p & 7;
    int j = q * 8 + jj;
    const float* a = (g == 0) ? bi0 : (g == 1) ? bi1 : (g == 2) ? bi2 : bi3;
    const float* b = (g == 0) ? bh0 : (g == 1) ? bh1 : (g == 2) ? bh2 : bh3;
    bias[p] = a[j] + b[j];
}

// ---------------- chunked x_proj GEMM (unchanged) ----------------
__global__ __launch_bounds__(256, 2) void k_xproj(
    const float* __restrict__ x, const bf16_t* __restrict__ wxt,
    const float* __restrict__ bias, bf16_t* __restrict__ xp, int r_base)
{
    __shared__ __align__(16) bf16_t Al[8 * 64 * 8];
    __shared__ __align__(16) bf16_t Bl[8 * 64 * 8];
    const int tid = threadIdx.x;
    const int n0 = blockIdx.x * 128;
    const int r0 = r_base + blockIdx.y * 128;
    const int wv = tid >> 6;
    const int lane = tid & 63;
    const int mq = wv >> 1, nq = wv & 1;
    f32x4 acc[4][4] = {};

    for (int kk = 0; kk < I_DIM; kk += 32) {
        __syncthreads();
        #pragma unroll
        for (int sidx = 0; sidx < 2; ++sidx) {
            int s = tid + sidx * 256;
            int mt = s >> 6, l = s & 63;
            int m = l & 15, kb = (l >> 4) * 8;
            int r = r0 + mt * 16 + m;
            int b = r & 63, si = r >> 6;
            const float* gp = x + ((size_t)(b * S_DIM + si)) * I_DIM + kk + kb;
            float4 v0 = *(const float4*)gp;
            float4 v1 = *(const float4*)(gp + 4);
            bf16x8 a;
            a[0] = (bf16_t)v0.x; a[1] = (bf16_t)v0.y; a[2] = (bf16_t)v0.z; a[3] = (bf16_t)v0.w;
            a[4] = (bf16_t)v1.x; a[5] = (bf16_t)v1.y; a[6] = (bf16_t)v1.z; a[7] = (bf16_t)v1.w;
            *(bf16x8*)&Al[s * 8] = a;
            bf16x8 bv = *(const bf16x8*)(wxt + (size_t)(n0 + mt * 16 + m) * I_DIM + kk + kb);
            *(bf16x8*)&Bl[s * 8] = bv;
        }
        __syncthreads();
        bf16x8 af[4], bfr[4];
        #pragma unroll
        for (int mt = 0; mt < 4; ++mt) af[mt]  = *(bf16x8*)&Al[((mq * 4 + mt) * 64 + lane) * 8];
        #pragma unroll
        for (int nt = 0; nt < 4; ++nt) bfr[nt] = *(bf16x8*)&Bl[((nq * 4 + nt) * 64 + lane) * 8];
        #pragma unroll
        for (int mt = 0; mt < 4; ++mt)
            #pragma unroll
            for (int nt = 0; nt < 4; ++nt)
                acc[mt][nt] = __builtin_amdgcn_mfma_f32_16x16x32_bf16(af[mt], bfr[nt], acc[mt][nt], 0, 0, 0);
    }
    const int l15 = lane & 15, quad = lane >> 4;
    #pragma unroll
    for (int nt = 0; nt < 4; ++nt) {
        int col = n0 + nq * 64 + nt * 16 + l15;
        float bv = bias[col];
        #pragma unroll
        for (int mt = 0; mt < 4; ++mt)
            #pragma unroll
            for (int r = 0; r < 4; ++r) {
                int row = r0 - r_base + mq * 64 + mt * 16 + quad * 4 + r;
                xp[(size_t)row * G4 + col] = (bf16_t)(acc[mt][nt][r] + bv);
            }
    }
}

// ---------------- one LSTM time-step per launch ----------------
// Kernel boundary = device-wide barrier + cross-XCD coherence (dispatch-end
// release, dispatch-start acquire). No flags, no spins, no sc0/sc1: the
// R2-R6 in-kernel agent-scope barrier cost ~11-14 us/step across four
// different implementations and resisted modeling — replaced by the known
// ~2 us AQL replay gap.
// Grid 64 WGs x 256 thr. WG q2 owns 64 packed cols; wave w: bh=w&1 (batch
// half), cb=w>>1 (32-col block) -> q = q2*2+cb. B from whtf (global, frag
// order, coalesced 1KB/inst). A (h) from slot t&1, written to slot (t+1)&1
// in A-frag order with NORMAL stores. c-state in address-stable f32 buffer.
__global__ __launch_bounds__(256, 1) void k_step(
    const bf16_t* __restrict__ whtf, const bf16_t* __restrict__ xp_t,
    const bf16_t* __restrict__ h_t, bf16_t* __restrict__ h_n,
    float* __restrict__ cstbuf, float* __restrict__ out, int write_out)
{
    __shared__ __align__(16) bf16_t Hlds[1024];   // 4 waves x 256 bf16
    const int tid = threadIdx.x;
    const int w = tid >> 6;
    const int lane = tid & 63;
    const int bh = w & 1;
    const int cb = w >> 1;
    const int q2 = blockIdx.x;
    const int q = q2 * 2 + cb;

    const int col  = lane & 31;
    const int ksel = lane >> 5;
    const int gt   = (lane >> 3) & 3;  // 0:i 1:f 2:g 3:o
    const int jj   = lane & 7;

    int rrow[16];
    #pragma unroll
    for (int r = 0; r < 16; ++r) rrow[r] = (r & 3) + 8 * (r >> 2) + 4 * ksel;

    // xp + c-state loads (issue early, consumed in epilogue)
    bf16_t xpr[16];
    #pragma unroll
    for (int r = 0; r < 16; ++r)
        xpr[r] = xp_t[(size_t)(bh * 32 + rrow[r]) * G4 + q * 32 + col];
    float cst[16];
    if (gt == 0) {
        #pragma unroll
        for (int r = 0; r < 16; ++r)
            cst[r] = cstbuf[(bh * 32 + rrow[r]) * H_DIM + q * 8 + jj];
    }

    const bf16_t* ab = h_t + (bh << 15) + (lane << 3);          // stride 512/ks
    const bf16_t* bb = whtf + ((size_t)q << 15) + (lane << 3);  // stride 512/ks

    // 8-deep pipelined A+B windows, 4 independent MFMA chains.
    bf16x8 ar[8], br[8];
    #pragma unroll
    for (int i = 0; i < 8; ++i) {
        ar[i] = *(const bf16x8*)(ab + i * 512);
        br[i] = *(const bf16x8*)(bb + i * 512);
    }
    f32x16 acc0 = {}, acc1 = {}, acc2 = {}, acc3 = {};
    #pragma unroll
    for (int ks = 0; ks < 64; ++ks) {
        bf16x8 a = ar[ks & 7];
        bf16x8 b = br[ks & 7];
        if (ks < 56) {
            ar[ks & 7] = *(const bf16x8*)(ab + (ks + 8) * 512);
            br[ks & 7] = *(const bf16x8*)(bb + (ks + 8) * 512);
        }
        if ((ks & 3) == 0)      acc0 = __builtin_amdgcn_mfma_f32_32x32x16_bf16(a, b, acc0, 0, 0, 0);
        else if ((ks & 3) == 1) acc1 = __builtin_amdgcn_mfma_f32_32x32x16_bf16(a, b, acc1, 0, 0, 0);
        else if ((ks & 3) == 2) acc2 = __builtin_amdgcn_mfma_f32_32x32x16_bf16(a, b, acc2, 0, 0, 0);
        else                    acc3 = __builtin_amdgcn_mfma_f32_32x32x16_bf16(a, b, acc3, 0, 0, 0);
    }
    f32x16 accs = acc0 + acc1 + acc2 + acc3;

    float act[16];
    #pragma unroll
    for (int r = 0; r < 16; ++r) {
        float pre = accs[r] + (float)xpr[r];
        act[r] = (gt == 2) ? tanh_fast(pre) : sigm(pre);
    }

    // c/h update on i-lanes; h redistributed via per-wave LDS scratch.
    #pragma unroll
    for (int r = 0; r < 16; ++r) {
        float fv = __shfl_xor(act[r], 8, 64);
        float gv = __shfl_xor(act[r], 16, 64);
        float ov = __shfl_xor(act[r], 24, 64);
        if (gt == 0) {
            float cn = fv * cst[r] + act[r] * gv;
            float hv = ov * tanh_fast(cn);
            Hlds[w * 256 + rrow[r] * 8 + jj] = (bf16_t)hv;
            cstbuf[(bh * 32 + rrow[r]) * H_DIM + q * 8 + jj] = cn;
            if (write_out) {
                int rowg = bh * 32 + rrow[r];
                int j = q * 8 + jj;
                out[rowg * H_DIM + j] = hv;            // h_T
                out[65536 + rowg * H_DIM + j] = cn;    // c_T
            }
        }
    }
    asm volatile("s_waitcnt lgkmcnt(0)" ::: "memory");  // intra-wave ds_write->ds_read

    // h_n write: this wave's output = contiguous 512 B in A-frag layout
    //   [bh][ks=q2][lane' = m + 32*cb][8], one u64 per lane, normal store.
    uint64_t v = *(const uint64_t*)&Hlds[w * 256 + lane * 4];
    ((uint64_t*)h_n)[(bh << 13) + (q2 << 7) + (cb << 6) + lane] = v;
}

extern "C" void kernel_launch(void* const* d_in, const int* in_sizes, int n_in,
                              void* d_out, int out_size, void* d_ws, size_t ws_size,
                              hipStream_t stream) {
    const float* x   = (const float*)d_in[0];
    const float* wii = (const float*)d_in[1];
    const float* bii = (const float*)d_in[2];
    const float* whi = (const float*)d_in[3];
    const float* bhi = (const float*)d_in[4];
    const float* wif = (const float*)d_in[5];
    const float* bif = (const float*)d_in[6];
    const float* whf = (const float*)d_in[7];
    const float* bhf = (const float*)d_in[8];
    const float* wig = (const float*)d_in[9];
    const float* big = (const float*)d_in[10];
    const float* whg = (const float*)d_in[11];
    const float* bhg = (const float*)d_in[12];
    const float* wio = (const float*)d_in[13];
    const float* bio = (const float*)d_in[14];
    const float* who = (const float*)d_in[15];
    const float* bho = (const float*)d_in[16];

    char* ws = (char*)d_ws;
    bf16_t*  wxt   = (bf16_t*)(ws + O_WXT);
    bf16_t*  whtf  = (bf16_t*)(ws + O_WHTF);
    float*   bias  = (float*)(ws + O_BIAS);
    float*   cstb  = (float*)(ws + O_CST);
    bf16_t*  hbuf  = (bf16_t*)(ws + O_HBUF);
    bf16_t*  xp    = (bf16_t*)(ws + O_XP);

    hipMemsetAsync(hbuf, 0, 128 * 1024, stream);   // h0 = 0 (slot 0, frag order)
    hipMemsetAsync(cstb, 0, 256 * 1024, stream);   // c0 = 0

    k_pack_wx<<<8192, 256, 0, stream>>>(wii, wif, wig, wio, wxt);
    k_pack_whf<<<16384, 256, 0, stream>>>(whi, whf, whg, who, whtf);
    k_pack_bias<<<16, 256, 0, stream>>>(bii, bhi, bif, bhf, big, bhg, bio, bho, bias);

    float* out = (float*)d_out;
    for (int c = 0; c < NCHUNK; ++c) {
        k_xproj<<<dim3(32, CHUNK * 64 / 128), 256, 0, stream>>>(x, wxt, bias, xp, c * CHUNK * 64);
        for (int tl = 0; tl < CHUNK; ++tl) {
            int t = c * CHUNK + tl;
            k_step<<<64, 256, 0, stream>>>(
                whtf, xp + (size_t)tl * 64 * G4,
                hbuf + (size_t)(t & 1) * 65536,
                hbuf + (size_t)((t + 1) & 1) * 65536,
                cstb, out, (t == S_DIM - 1) ? 1 : 0);
        }
    }
}